// Round 4
// baseline (6581.683 us; speedup 1.0000x reference)
//
#include <hip/hip_runtime.h>
#include <stdint.h>

// ---------------------------------------------------------------------------
// 3-layer packed-sequence LSTM, B=64 T=2048 D=40 H=164, FC->7. fp32 in/out.
//
// Single fused staircase kernel, launched 21x (no inter-block sync, no hang):
//   launch i:  gemm-blocks (l, ch=i-2l)   : input projections -> gx  (MFMA)
//              krec-blocks (l, ch=i-2l-1) : 128 recurrence steps     (MFMA)
//   All producer->consumer edges cross a launch boundary.
//   gx AND hring are parity double-buffered: kgemm(l,ch+1) runs in the same
//   launch as krec(l,ch) -> single-buffered gx raced (round-3 bug, 6e-2).
//
// krec: 4 batches/block, 256 thr (4 waves). gates = h[4x164] @ W_hh^T via
// mfma_f32_16x16x32_f16: 41 N-tiles x 6 K-steps = 246 MFMA/step.
// W_hh register-resident: 10 tiles x 6 k x half8 = 240 regs/wave (unified
// VGPR/AGPR file, 1 block/CU); tile 40 streamed from LDS by wave 0.
// Elementwise lane-packed: gates -> LDS [grow][4] f32, ew threads read
// conflict-free (cell-linear index == tid), ~3 cells/thread, c/h in regs.
// ---------------------------------------------------------------------------

#define TT 2048
#define BB 64
#define GG 656   // 4*H
#define HH 164
#define CC 128   // timesteps per chunk
#define NCH 16   // TT/CC
#define NBG 16   // 64/4 batch groups
#define NLAUNCH 21  // krec(2,15) at 15+2*2+1 = 20

typedef _Float16 half2v __attribute__((ext_vector_type(2)));
typedef _Float16 half8  __attribute__((ext_vector_type(8)));
typedef float    f32x4  __attribute__((ext_vector_type(4)));

// ---- workspace layout (bytes) ----
#define SZ_W16   (3*GG*192*2)                  // f16 [3][656][192]
#define OFF_WIH  0
#define OFF_WHH  (SZ_W16)
#define OFF_GX   (2*SZ_W16)
#define SZ_GX    ((size_t)3*NBG*2*CC*GG*4*2)   // f16 [3][16][2 slots][128][2624]
#define OFF_HR   (OFF_GX + SZ_GX)
#define SZ_HR    ((size_t)2*2*BB*CC*168*2)     // f16 [2][2 slots][64][128][168]
#define OFF_SC   (OFF_HR + SZ_HR)
#define SZ_SC    (3*BB*HH*4)                   // f32 cell state
#define OFF_SH   (OFF_SC + SZ_SC)
#define SZ_SH    (3*BB*168*2)                  // f16 hidden state
#define WS_TOTAL (OFF_SH + SZ_SH)              // ~53.4 MiB

__device__ __forceinline__ float sigf(float x)   { return 1.0f/(1.0f + __expf(-x)); }
__device__ __forceinline__ float tanhf_(float x) { return 2.0f/(1.0f + __expf(-2.0f*x)) - 1.0f; }
__device__ __forceinline__ int clamplen(int v)   { return v < 1 ? 1 : (v > TT ? TT : v); }

// ---------------------------------------------------------------------------
// weight prep: fp32 -> f16, K padded to 192 halves (zeros), [3][656][192]
// ---------------------------------------------------------------------------
__global__ void kprep_w(const float* wih0, const float* whh0,
                        const float* wih1, const float* whh1,
                        const float* wih2, const float* whh2,
                        _Float16* wih16, _Float16* whh16) {
  int i = threadIdx.x + blockIdx.x * blockDim.x;
  if (i >= 3*GG*192) return;
  int l = i / (GG*192);
  int r = i - l*(GG*192);
  int j = r / 192;
  int k = r - j*192;
  float vi = 0.f, vh = 0.f;
  if (l == 0) {
    if (k < 40) vi = wih0[j*40 + k];
    if (k < HH) vh = whh0[j*HH + k];
  } else if (l == 1) {
    if (k < HH) vi = wih1[j*HH + k];
    if (k < HH) vh = whh1[j*HH + k];
  } else {
    if (k < HH) vi = wih2[j*HH + k];
    if (k < HH) vh = whh2[j*HH + k];
  }
  wih16[i] = (_Float16)vi;
  whh16[i] = (_Float16)vh;
}

// ---------------------------------------------------------------------------
// fused staircase step. grid 96: blocks 0..47 = krec(l,bg), 48..95 = gemm(l,bg)
// ---------------------------------------------------------------------------
__launch_bounds__(256, 1)
__global__ void kstep(int step, const int* lengths, const float* x,
                      const float* b0, const float* b1, const float* b2,
                      const uint16_t* wih16, const uint16_t* whh16,
                      uint16_t* gx, uint16_t* hring,
                      float* state_c, uint16_t* state_h) {
  const int tid  = threadIdx.x;
  const int lane = tid & 63, wv = tid >> 6;
  const int quad = lane >> 4, n15 = lane & 15;

  // [0..1599] Ah 16x100dw | [1600..3199] wt40 16x100dw | [3200..5823] gates 656x4 f32
  __shared__ __align__(16) uint32_t sm[5824];

  if (blockIdx.x < 48) {
    // ===================== RECURRENCE: (layer l, 4-batch group bg) ==========
    const int l  = blockIdx.x >> 4, bg = blockIdx.x & 15;
    const int ch = step - 2*l - 1;
    if (ch < 0 || ch >= NCH) return;
    const int b0i = bg*4;
    const int j0 = tid >> 2, b4 = tid & 3;
    const int myb = b0i + b4;
    const int lenb = clamplen(lengths[myb]);
    int mx = clamplen(lengths[b0i]);
    { int v = clamplen(lengths[b0i+1]); if (v > mx) mx = v;
      v = clamplen(lengths[b0i+2]); if (v > mx) mx = v;
      v = clamplen(lengths[b0i+3]); if (v > mx) mx = v; }
    const int t0 = ch*CC;
    if (t0 >= mx) return;
    int t1 = t0 + CC; if (t1 > mx) t1 = mx;

    // ---- W_hh fragments: 10 register-resident tiles/wave + tile 40 via LDS
    half8 wf[10][6];
    #pragma unroll
    for (int idx = 0; idx < 10; ++idx) {
      const int nt = wv + 4*idx;
      #pragma unroll
      for (int k = 0; k < 6; ++k)
        wf[idx][k] = *(const half8*)(whh16 +
            ((size_t)(l*GG + nt*16 + n15)*192 + k*32 + quad*8));
    }
    for (int i2 = tid; i2 < 16*96; i2 += 256) {
      int row = i2 / 96, dw = i2 - row*96;
      sm[1600 + row*100 + dw] =
          ((const uint32_t*)whh16)[(size_t)(l*GG + 640 + row)*96 + dw];
    }
    // Ah K-pad (halves 164..191 of rows 0..3) = 0
    if (tid < 64) { int rr = tid >> 4, dwp = tid & 15;
                    if (dwp < 14) sm[rr*100 + 82 + dwp] = 0; }

    // ---- state ----
    float creg[3]; uint16_t hreg[3];
    #pragma unroll
    for (int s = 0; s < 3; ++s) { creg[s] = 0.f; hreg[s] = 0; }
    if (ch > 0) {
      #pragma unroll
      for (int s = 0; s < 3; ++s) {
        int j = j0 + 64*s;
        if (j < HH) {
          creg[s] = state_c[(size_t)(l*BB + myb)*HH + j];
          hreg[s] = state_h[(size_t)(l*BB + myb)*168 + j];
        }
      }
    }
    #pragma unroll
    for (int s = 0; s < 3; ++s) {
      int j = j0 + 64*s;
      if (j < HH) ((uint16_t*)sm)[b4*200 + j] = hreg[s];
    }

    const uint16_t* gxb = gx + (size_t)((l*NBG + bg)*2 + (ch & 1))*CC*GG*4;
    uint16_t* hrb = (l < 2)
        ? hring + (size_t)((l*2 + (ch & 1))*BB + myb)*CC*168 : (uint16_t*)0;
    float* gatesf = (float*)(sm + 3200);
    const uint16_t* AhH  = (const uint16_t*)sm;
    const uint16_t* wt40 = (const uint16_t*)(sm + 1600);
    __syncthreads();

    for (int t = t0; t < t1; ++t) {
      const int tl = t - t0;
      // A fragments (rows 4..15 garbage - their D rows are never read)
      half8 a[6];
      #pragma unroll
      for (int k = 0; k < 6; ++k)
        a[k] = *(const half8*)(AhH + n15*200 + k*32 + quad*8);
      // gx prefetch (consumed in ew): cell-linear = j*4+b4 = tid+256s
      uint2 gxv[3];
      const uint16_t* gxt = gxb + (size_t)tl*GG*4;
      #pragma unroll
      for (int s = 0; s < 3; ++s) {
        int ci = tid + 256*s;
        if (ci < GG) gxv[s] = *(const uint2*)(gxt + ci*4);
      }
      // MFMA: 41 N-tiles x 6 K-steps
      f32x4 acc[11];
      #pragma unroll
      for (int q = 0; q < 11; ++q) acc[q] = (f32x4){0.f,0.f,0.f,0.f};
      #pragma unroll
      for (int k = 0; k < 6; ++k) {
        #pragma unroll
        for (int idx = 0; idx < 10; ++idx)
          acc[idx] = __builtin_amdgcn_mfma_f32_16x16x32_f16(a[k], wf[idx][k],
                                                            acc[idx], 0, 0, 0);
        if (wv == 0) {
          half8 bw = *(const half8*)(wt40 + n15*200 + k*32 + quad*8);
          acc[10] = __builtin_amdgcn_mfma_f32_16x16x32_f16(a[k], bw,
                                                           acc[10], 0, 0, 0);
        }
      }
      // gates -> LDS [grow][m]: lanes 0..15 hold m=0..3 in regs 0..3
      if (quad == 0) {
        #pragma unroll
        for (int idx = 0; idx < 10; ++idx)
          *(f32x4*)(gatesf + ((wv + 4*idx)*16 + n15)*4) = acc[idx];
        if (wv == 0) *(f32x4*)(gatesf + (640 + n15)*4) = acc[10];
      }
      __syncthreads();
      // elementwise (i,f,g,o), c/h in regs, freeze at t >= len
      #pragma unroll
      for (int s = 0; s < 3; ++s) {
        int j = j0 + 64*s;
        if (j < HH) {
          int ci = tid + 256*s;
          half2v p01 = __builtin_bit_cast(half2v, gxv[s].x);
          half2v p23 = __builtin_bit_cast(half2v, gxv[s].y);
          float gi = gatesf[ci]        + (float)p01[0];
          float gf = gatesf[GG + ci]   + (float)p01[1];
          float gg = gatesf[2*GG + ci] + (float)p23[0];
          float go = gatesf[3*GG + ci] + (float)p23[1];
          if (t < lenb) {
            float c = sigf(gf)*creg[s] + sigf(gi)*tanhf_(gg);
            creg[s] = c;
            hreg[s] = __builtin_bit_cast(uint16_t,
                          (_Float16)(sigf(go)*tanhf_(c)));
          }
          ((uint16_t*)sm)[b4*200 + j] = hreg[s];
          if (l < 2) hrb[(size_t)tl*168 + j] = hreg[s];
        }
      }
      __syncthreads();
    }
    // persist state
    #pragma unroll
    for (int s = 0; s < 3; ++s) {
      int j = j0 + 64*s;
      if (j < HH) {
        state_c[(size_t)(l*BB + myb)*HH + j] = creg[s];
        state_h[(size_t)(l*BB + myb)*168 + j] = hreg[s];
      }
    }

  } else {
    // ===================== INPUT PROJECTION: (layer l, group bg) ============
    const int gb = blockIdx.x - 48;
    const int l  = gb >> 4, bg = gb & 15;
    const int ch = step - 2*l;
    if (ch < 0 || ch >= NCH) return;
    const float* bp = (l == 0) ? b0 : ((l == 1) ? b1 : b2);
    int len4[4];
    #pragma unroll
    for (int q = 0; q < 4; ++q) len4[q] = clamplen(lengths[bg*4 + q]);

    float biasv[11]; int gjv[11];
    #pragma unroll
    for (int idx = 0; idx < 11; ++idx) {
      const int nt = (idx < 10) ? (wv + 4*idx) : 40;
      const int wrow = nt*16 + n15;
      biasv[idx] = bp[wrow];
      const int g = (wrow >= 492) ? 3 : ((wrow >= 328) ? 2 : ((wrow >= 164) ? 1 : 0));
      gjv[idx] = (wrow - g*164)*16 + g;
    }
    const int Kt = (l == 0) ? 2 : 6;
    uint16_t* gxo = gx + (size_t)((l*NBG + bg)*2 + (ch & 1))*CC*GG*4;
    const uint16_t* asrc = (const uint16_t*)sm;
    const int ntiles = (wv == 0) ? 11 : 10;

    for (int iter = 0; iter < 16; ++iter) {
      const int b4 = iter >> 2, st = iter & 3;
      const int b = bg*4 + b4;
      if (ch*CC >= len4[b4]) continue;          // uniform across block
      // stage A-tile: 32 timesteps x K halves (pad zero)
      if (l == 0) {
        for (int i2 = tid; i2 < 32*32; i2 += 256) {
          int row = i2 >> 5, dw = i2 & 31;
          int t = ch*CC + st*32 + row;
          uint32_t v = 0;
          if (dw < 20) {
            const float* xs = x + ((size_t)b*TT + t)*40 + dw*2;
            half2v p; p[0] = (_Float16)xs[0]; p[1] = (_Float16)xs[1];
            v = __builtin_bit_cast(uint32_t, p);
          }
          sm[row*100 + dw] = v;
        }
      } else {
        const uint32_t* hbs = (const uint32_t*)hring +
            (size_t)(((l-1)*2 + (ch & 1))*BB + b)*CC*84;
        for (int i2 = tid; i2 < 32*96; i2 += 256) {
          int row = i2 / 96, dw = i2 - row*96;
          uint32_t v = 0;
          if (dw < 84) v = hbs[(size_t)(st*32 + row)*84 + dw];
          sm[row*100 + dw] = v;
        }
      }
      __syncthreads();
      for (int idx = 0; idx < ntiles; ++idx) {
        const int nt = (idx < 10) ? (wv + 4*idx) : 40;
        const uint16_t* bsrc = wih16 + (size_t)(l*GG + nt*16 + n15)*192;
        f32x4 a0 = {0.f,0.f,0.f,0.f}, a1 = {0.f,0.f,0.f,0.f};
        for (int kk = 0; kk < Kt; ++kk) {
          half8 bf  = *(const half8*)(bsrc + kk*32 + quad*8);
          half8 af0 = *(const half8*)(asrc + n15*200      + kk*32 + quad*8);
          half8 af1 = *(const half8*)(asrc + (n15+16)*200 + kk*32 + quad*8);
          a0 = __builtin_amdgcn_mfma_f32_16x16x32_f16(af0, bf, a0, 0, 0, 0);
          a1 = __builtin_amdgcn_mfma_f32_16x16x32_f16(af1, bf, a1, 0, 0, 0);
        }
        const float bias = biasv[idx];
        const int so = gjv[idx] + b4*4;
        #pragma unroll
        for (int r = 0; r < 4; ++r) {
          const int tla = st*32 + quad*4 + r;
          gxo[(size_t)tla*2624 + so] =
              __builtin_bit_cast(uint16_t, (_Float16)(a0[r] + bias));
          gxo[(size_t)(tla+16)*2624 + so] =
              __builtin_bit_cast(uint16_t, (_Float16)(a1[r] + bias));
        }
      }
      __syncthreads();
    }
  }
}

// ---------------------------------------------------------------------------
// FC epilogue on layer-2 final hidden state
// ---------------------------------------------------------------------------
__global__ void kfc(const float* fcw, const float* fcb,
                    const uint16_t* state_h, float* out) {
  int b = blockIdx.x, o = threadIdx.x;
  if (o >= 7) return;
  const uint16_t* h16 = state_h + (size_t)(2*BB + b)*168;
  float s = fcb[o];
  for (int m = 0; m < HH; ++m) {
    _Float16 hv = __builtin_bit_cast(_Float16, h16[m]);
    s += fcw[o*HH + m] * (float)hv;
  }
  out[b*7 + o] = s;
}

// ---------------------------------------------------------------------------
extern "C" void kernel_launch(void* const* d_in, const int* in_sizes, int n_in,
                              void* d_out, int out_size, void* d_ws, size_t ws_size,
                              hipStream_t stream) {
  const float* x      = (const float*)d_in[0];
  const int*  lengths = (const int*)  d_in[1];
  const float* wih0   = (const float*)d_in[2];
  const float* whh0   = (const float*)d_in[3];
  const float* b0     = (const float*)d_in[4];
  const float* wih1   = (const float*)d_in[5];
  const float* whh1   = (const float*)d_in[6];
  const float* b1     = (const float*)d_in[7];
  const float* wih2   = (const float*)d_in[8];
  const float* whh2   = (const float*)d_in[9];
  const float* b2     = (const float*)d_in[10];
  const float* fcw    = (const float*)d_in[11];
  const float* fcb    = (const float*)d_in[12];

  if (ws_size < (size_t)WS_TOTAL) return;      // loud, clean failure

  char* ws = (char*)d_ws;
  _Float16* wih16 = (_Float16*)(ws + OFF_WIH);
  _Float16* whh16 = (_Float16*)(ws + OFF_WHH);
  uint16_t* gxw   = (uint16_t*)(ws + OFF_GX);
  uint16_t* hrw   = (uint16_t*)(ws + OFF_HR);
  float*    scw   = (float*)   (ws + OFF_SC);
  uint16_t* shw   = (uint16_t*)(ws + OFF_SH);

  hipLaunchKernelGGL(kprep_w, dim3((3*GG*192 + 255)/256), dim3(256), 0, stream,
                     wih0, whh0, wih1, whh1, wih2, whh2, wih16, whh16);

  for (int i = 0; i < NLAUNCH; ++i) {
    hipLaunchKernelGGL(kstep, dim3(96), dim3(256), 0, stream,
                       i, lengths, x, b0, b1, b2,
                       (const uint16_t*)wih16, (const uint16_t*)whh16,
                       gxw, hrw, scw, shw);
  }

  hipLaunchKernelGGL(kfc, dim3(64), dim3(64), 0, stream,
                     fcw, fcb, shw, (float*)d_out);
}

// Round 5
// 5550.120 us; speedup vs baseline: 1.1859x; 1.1859x over previous
//
#include <hip/hip_runtime.h>
#include <stdint.h>

// ---------------------------------------------------------------------------
// 3-layer packed-sequence LSTM, B=64 T=2048 D=40 H=164, FC->7. fp32 in/out.
//
// Staircase-pipelined launch chain (no inter-block sync):
//   launch i:  gemm-blocks (l, ch=i-2l)   : input projections -> gx  (MFMA)
//              krec-blocks (l, ch=i-2l-1) : 128 recurrence steps     (MFMA)
// gx and hring parity double-buffered (round-3 race fix).
//
// Round-5 changes (latency/drain fixes, round-4 was 6500 cy/step all-idle):
//  1. RAW barriers (inline asm "s_waitcnt lgkmcnt(0); s_barrier") in the hot
//     loops: __syncthreads drains vmcnt(0) every step (hring stores + any gx
//     prefetch). All cross-block consumers are in the NEXT launch; kernel-end
//     flush covers global stores. LDS ordering needs lgkmcnt only.
//  2. 2-step gx register prefetch (issue at ew(t), consume at ew(t+2)):
//     ~1400 cy in flight > 900 cy HBM miss latency.
//  3. gx layout D-native [b4][t][grow]: kgemm stores coalesce into 32B runs
//     (round-4 cell-interleave scattered 2B stores -> 107 MB WRITE_SIZE).
//  4. A-fragment LDS row stride 100 -> 102 dwords (8-way conflict -> ~2-way).
//  5. v_rcp_f32 (builtin) for sigmoid/tanh instead of full fp32 divide.
// ---------------------------------------------------------------------------

#define TT 2048
#define BB 64
#define GG 656   // 4*H
#define HH 164
#define CC 128   // timesteps per chunk
#define NCH 16   // TT/CC
#define NBG 16   // 64/4 batch groups
#define NLAUNCH 21

typedef _Float16 half2v __attribute__((ext_vector_type(2)));
typedef _Float16 half8  __attribute__((ext_vector_type(8)));
typedef float    f32x4  __attribute__((ext_vector_type(4)));

// ---- workspace layout (bytes) ----
#define SZ_W16   (3*GG*192*2)                  // f16 [3][656][192]
#define OFF_WIH  0
#define OFF_WHH  (SZ_W16)
#define OFF_GX   (2*SZ_W16)
#define SZ_GX    ((size_t)3*NBG*2*CC*GG*4*2)   // f16 [3][16][2 par][4][128][656]
#define OFF_HR   (OFF_GX + SZ_GX)
#define SZ_HR    ((size_t)2*2*BB*CC*168*2)     // f16 [2][2 par][64][128][168]
#define OFF_SC   (OFF_HR + SZ_HR)
#define SZ_SC    (3*BB*HH*4)                   // f32 cell state
#define OFF_SH   (OFF_SC + SZ_SC)
#define SZ_SH    (3*BB*168*2)                  // f16 hidden state
#define WS_TOTAL (OFF_SH + SZ_SH)

// raw barrier: LDS-only wait; vmem stays in flight (consumers are next launch)
#define BARRIER() __asm__ volatile("s_waitcnt lgkmcnt(0)\ns_barrier" ::: "memory")

__device__ __forceinline__ float rcpf(float x) { return __builtin_amdgcn_rcpf(x); }
__device__ __forceinline__ float sigf(float x)   { return rcpf(1.0f + __expf(-x)); }
__device__ __forceinline__ float tanhf_(float x) { return 2.0f*rcpf(1.0f + __expf(-2.0f*x)) - 1.0f; }
__device__ __forceinline__ int clamplen(int v)   { return v < 1 ? 1 : (v > TT ? TT : v); }
__device__ __forceinline__ float h2f(uint16_t u) {
  return (float)__builtin_bit_cast(_Float16, u);
}

// ---------------------------------------------------------------------------
__global__ void kprep_w(const float* wih0, const float* whh0,
                        const float* wih1, const float* whh1,
                        const float* wih2, const float* whh2,
                        _Float16* wih16, _Float16* whh16) {
  int i = threadIdx.x + blockIdx.x * blockDim.x;
  if (i >= 3*GG*192) return;
  int l = i / (GG*192);
  int r = i - l*(GG*192);
  int j = r / 192;
  int k = r - j*192;
  float vi = 0.f, vh = 0.f;
  if (l == 0) {
    if (k < 40) vi = wih0[j*40 + k];
    if (k < HH) vh = whh0[j*HH + k];
  } else if (l == 1) {
    if (k < HH) vi = wih1[j*HH + k];
    if (k < HH) vh = whh1[j*HH + k];
  } else {
    if (k < HH) vi = wih2[j*HH + k];
    if (k < HH) vh = whh2[j*HH + k];
  }
  wih16[i] = (_Float16)vi;
  whh16[i] = (_Float16)vh;
}

// ---------------------------------------------------------------------------
// fused staircase step. grid 96: blocks 0..47 = krec(l,bg), 48..95 = gemm(l,bg)
// ---------------------------------------------------------------------------
__launch_bounds__(256, 1)
__global__ void kstep(int step, const int* lengths, const float* x,
                      const float* b0, const float* b1, const float* b2,
                      const uint16_t* wih16, const uint16_t* whh16,
                      uint16_t* gx, uint16_t* hring,
                      float* state_c, uint16_t* state_h) {
  const int tid  = threadIdx.x;
  const int lane = tid & 63, wv = tid >> 6;
  const int quad = lane >> 4, n15 = lane & 15;

  // krec: [0..1631] A/h 16 rows x 102 dw | [1632..4255] gates 656x4 f32
  // gemm: [0..3263] A-tile 32 rows x 102 dw
  __shared__ __align__(16) uint32_t sm[4256];

  if (blockIdx.x < 48) {
    // ===================== RECURRENCE: (layer l, 4-batch group bg) ==========
    const int l  = blockIdx.x >> 4, bg = blockIdx.x & 15;
    const int ch = step - 2*l - 1;
    if (ch < 0 || ch >= NCH) return;
    const int b0i = bg*4;
    const int par = ch & 1;
    int mx = clamplen(lengths[b0i]);
    { int v = clamplen(lengths[b0i+1]); if (v > mx) mx = v;
      v = clamplen(lengths[b0i+2]); if (v > mx) mx = v;
      v = clamplen(lengths[b0i+3]); if (v > mx) mx = v; }
    const int t0 = ch*CC;
    if (t0 >= mx) return;
    int t1 = t0 + CC; if (t1 > mx) t1 = mx;
    const int nsteps = t1 - t0;

    // per-thread cell mapping: cell = tid + 256*s, clamped (dup lanes benign)
    int b4s[3], jss[3], lenb[3];
    size_t gxoff[3], hroff[3];
    #pragma unroll
    for (int s = 0; s < 3; ++s) {
      int c = tid + 256*s; if (c > GG - 1) c = GG - 1;
      b4s[s] = c / HH; jss[s] = c - b4s[s]*HH;
      lenb[s] = clamplen(lengths[b0i + b4s[s]]);
      gxoff[s] = (size_t)(b4s[s]*CC)*GG + jss[s];
      hroff[s] = ((size_t)((l*2 + par)*BB + b0i + b4s[s]))*CC*168 + jss[s];
    }
    const uint16_t* gxb = gx + (size_t)((l*NBG + bg)*2 + par)*CC*GG*4;

    // first two gx prefetches (overlap with weight-fragment loads)
    uint16_t gA[12], gB[12];
    #pragma unroll
    for (int s = 0; s < 3; ++s)
      #pragma unroll
      for (int g = 0; g < 4; ++g) {
        gA[s*4+g] = gxb[gxoff[s] + (size_t)0*GG + g*HH];
        gB[s*4+g] = gxb[gxoff[s] + (size_t)1*GG + g*HH];
      }

    // W_hh fragments: 11 tiles/wave (tile 40 redundant on all waves)
    half8 wf[11][6];
    #pragma unroll
    for (int idx = 0; idx < 11; ++idx) {
      const int nt = (idx < 10) ? (wv + 4*idx) : 40;
      #pragma unroll
      for (int k = 0; k < 6; ++k)
        wf[idx][k] = *(const half8*)(whh16 +
            ((size_t)(l*GG + nt*16 + n15)*192 + k*32 + quad*8));
    }

    // ---- h into LDS rows 0..3 (stride 204 halves), pad 164..191 zero ----
    uint16_t* AhU = (uint16_t*)sm;
    for (int i2 = tid; i2 < 4*192; i2 += 256) {
      int b4i = i2 / 192, j = i2 - b4i*192;
      uint16_t v = 0;
      if (ch > 0 && j < HH)
        v = state_h[(size_t)(l*BB + b0i + b4i)*168 + j];
      AhU[b4i*204 + j] = v;
    }
    // ---- c/h state regs ----
    float creg[3]; uint16_t hreg[3];
    #pragma unroll
    for (int s = 0; s < 3; ++s) {
      creg[s] = 0.f; hreg[s] = 0;
      if (ch > 0) {
        creg[s] = state_c[(size_t)(l*BB + b0i + b4s[s])*HH + jss[s]];
        hreg[s] = state_h[(size_t)(l*BB + b0i + b4s[s])*168 + jss[s]];
      }
    }

    float* gatesf = (float*)(sm + 1632);
    uint16_t* hr16 = hring;
    BARRIER();

#define STEPF(BUF, T)                                                         \
    {                                                                         \
      const int tl = (T) - t0;                                                \
      half8 a[6];                                                             \
      _Pragma("unroll") for (int k = 0; k < 6; ++k)                           \
        a[k] = *(const half8*)(AhU + n15*204 + k*32 + quad*8);                \
      f32x4 acc[11];                                                          \
      _Pragma("unroll") for (int q = 0; q < 11; ++q)                          \
        acc[q] = (f32x4){0.f,0.f,0.f,0.f};                                    \
      _Pragma("unroll") for (int k = 0; k < 6; ++k)                           \
        _Pragma("unroll") for (int idx = 0; idx < 11; ++idx)                  \
          acc[idx] = __builtin_amdgcn_mfma_f32_16x16x32_f16(a[k],             \
                         wf[idx][k], acc[idx], 0, 0, 0);                      \
      if (quad == 0) {                                                        \
        _Pragma("unroll") for (int idx = 0; idx < 10; ++idx)                  \
          *(f32x4*)(gatesf + ((wv + 4*idx)*16 + n15)*4) = acc[idx];           \
        if (wv == 0) *(f32x4*)(gatesf + (640 + n15)*4) = acc[10];             \
      }                                                                       \
      BARRIER();                                                              \
      _Pragma("unroll") for (int s = 0; s < 3; ++s) {                         \
        float gi = gatesf[(      jss[s])*4 + b4s[s]] + h2f(BUF[s*4+0]);       \
        float gf = gatesf[(HH  + jss[s])*4 + b4s[s]] + h2f(BUF[s*4+1]);       \
        float gg = gatesf[(2*HH+ jss[s])*4 + b4s[s]] + h2f(BUF[s*4+2]);       \
        float go = gatesf[(3*HH+ jss[s])*4 + b4s[s]] + h2f(BUF[s*4+3]);       \
        if ((T) < lenb[s]) {                                                  \
          float c = sigf(gf)*creg[s] + sigf(gi)*tanhf_(gg);                   \
          creg[s] = c;                                                        \
          hreg[s] = __builtin_bit_cast(uint16_t,                              \
                        (_Float16)(sigf(go)*tanhf_(c)));                      \
        }                                                                     \
        AhU[b4s[s]*204 + jss[s]] = hreg[s];                                   \
        if (l < 2) hr16[hroff[s] + (size_t)tl*168] = hreg[s];                 \
      }                                                                       \
      if (tl + 2 < CC) {                                                      \
        _Pragma("unroll") for (int s = 0; s < 3; ++s)                         \
          _Pragma("unroll") for (int g = 0; g < 4; ++g)                       \
            BUF[s*4+g] = gxb[gxoff[s] + (size_t)(tl+2)*GG + g*HH];            \
      }                                                                       \
      BARRIER();                                                              \
    }

    for (int i2 = 0; i2 < nsteps; i2 += 2) {
      STEPF(gA, t0 + i2);
      if (i2 + 1 < nsteps) STEPF(gB, t0 + i2 + 1);
    }
#undef STEPF

    // persist state
    #pragma unroll
    for (int s = 0; s < 3; ++s) {
      state_c[(size_t)(l*BB + b0i + b4s[s])*HH + jss[s]] = creg[s];
      state_h[(size_t)(l*BB + b0i + b4s[s])*168 + jss[s]] = hreg[s];
    }

  } else {
    // ===================== INPUT PROJECTION: (layer l, group bg) ============
    const int gb = blockIdx.x - 48;
    const int l  = gb >> 4, bg = gb & 15;
    const int ch = step - 2*l;
    if (ch < 0 || ch >= NCH) return;
    const int par = ch & 1;
    const float* bp = (l == 0) ? b0 : ((l == 1) ? b1 : b2);
    int len4[4];
    #pragma unroll
    for (int q = 0; q < 4; ++q) len4[q] = clamplen(lengths[bg*4 + q]);

    float biasv[11];
    #pragma unroll
    for (int idx = 0; idx < 11; ++idx) {
      const int nt = (idx < 10) ? (wv + 4*idx) : 40;
      biasv[idx] = bp[nt*16 + n15];
    }
    const int Kt = (l == 0) ? 2 : 6;
    uint16_t* gxo = gx + (size_t)((l*NBG + bg)*2 + par)*CC*GG*4;
    const uint16_t* asrc = (const uint16_t*)sm;
    const int ntiles = (wv == 0) ? 11 : 10;

    for (int iter = 0; iter < 16; ++iter) {
      const int b4 = iter >> 2, st = iter & 3;
      const int b = bg*4 + b4;
      if (ch*CC >= len4[b4]) continue;          // uniform across block
      // stage A-tile: 32 timesteps x K halves (stride 102 dw, pad zero)
      if (l == 0) {
        for (int i2 = tid; i2 < 32*32; i2 += 256) {
          int row = i2 >> 5, dw = i2 & 31;
          int t = ch*CC + st*32 + row;
          uint32_t v = 0;
          if (dw < 20) {
            const float* xs = x + ((size_t)b*TT + t)*40 + dw*2;
            half2v p; p[0] = (_Float16)xs[0]; p[1] = (_Float16)xs[1];
            v = __builtin_bit_cast(uint32_t, p);
          }
          sm[row*102 + dw] = v;
        }
      } else {
        const uint32_t* hbs = (const uint32_t*)hring +
            (size_t)(((l-1)*2 + par)*BB + b)*CC*84;
        for (int i2 = tid; i2 < 32*96; i2 += 256) {
          int row = i2 / 96, dw = i2 - row*96;
          uint32_t v = 0;
          if (dw < 84) v = hbs[(size_t)(st*32 + row)*84 + dw];
          sm[row*102 + dw] = v;
        }
      }
      BARRIER();
      for (int idx = 0; idx < ntiles; ++idx) {
        const int nt = (idx < 10) ? (wv + 4*idx) : 40;
        const int wrow = nt*16 + n15;
        const uint16_t* bsrc = wih16 + (size_t)(l*GG + wrow)*192;
        f32x4 a0 = {0.f,0.f,0.f,0.f}, a1 = {0.f,0.f,0.f,0.f};
        for (int kk = 0; kk < Kt; ++kk) {
          half8 bf  = *(const half8*)(bsrc + kk*32 + quad*8);
          half8 af0 = *(const half8*)(asrc + n15*204      + kk*32 + quad*8);
          half8 af1 = *(const half8*)(asrc + (n15+16)*204 + kk*32 + quad*8);
          a0 = __builtin_amdgcn_mfma_f32_16x16x32_f16(af0, bf, a0, 0, 0, 0);
          a1 = __builtin_amdgcn_mfma_f32_16x16x32_f16(af1, bf, a1, 0, 0, 0);
        }
        const float bias = biasv[idx];
        // D-native store: [b4][t][wrow], 16 consecutive wrow = 32B runs
        #pragma unroll
        for (int r = 0; r < 4; ++r) {
          const int tla = st*32 + quad*4 + r;
          gxo[(size_t)(b4*CC + tla)*GG + wrow] =
              __builtin_bit_cast(uint16_t, (_Float16)(a0[r] + bias));
          gxo[(size_t)(b4*CC + tla + 16)*GG + wrow] =
              __builtin_bit_cast(uint16_t, (_Float16)(a1[r] + bias));
        }
      }
      BARRIER();
    }
  }
}

// ---------------------------------------------------------------------------
__global__ void kfc(const float* fcw, const float* fcb,
                    const uint16_t* state_h, float* out) {
  int b = blockIdx.x, o = threadIdx.x;
  if (o >= 7) return;
  const uint16_t* h16 = state_h + (size_t)(2*BB + b)*168;
  float s = fcb[o];
  for (int m = 0; m < HH; ++m) s += fcw[o*HH + m] * h2f(h16[m]);
  out[b*7 + o] = s;
}

// ---------------------------------------------------------------------------
extern "C" void kernel_launch(void* const* d_in, const int* in_sizes, int n_in,
                              void* d_out, int out_size, void* d_ws, size_t ws_size,
                              hipStream_t stream) {
  const float* x      = (const float*)d_in[0];
  const int*  lengths = (const int*)  d_in[1];
  const float* wih0   = (const float*)d_in[2];
  const float* whh0   = (const float*)d_in[3];
  const float* b0     = (const float*)d_in[4];
  const float* wih1   = (const float*)d_in[5];
  const float* whh1   = (const float*)d_in[6];
  const float* b1     = (const float*)d_in[7];
  const float* wih2   = (const float*)d_in[8];
  const float* whh2   = (const float*)d_in[9];
  const float* b2     = (const float*)d_in[10];
  const float* fcw    = (const float*)d_in[11];
  const float* fcb    = (const float*)d_in[12];

  if (ws_size < (size_t)WS_TOTAL) return;

  char* ws = (char*)d_ws;
  _Float16* wih16 = (_Float16*)(ws + OFF_WIH);
  _Float16* whh16 = (_Float16*)(ws + OFF_WHH);
  uint16_t* gxw   = (uint16_t*)(ws + OFF_GX);
  uint16_t* hrw   = (uint16_t*)(ws + OFF_HR);
  float*    scw   = (float*)   (ws + OFF_SC);
  uint16_t* shw   = (uint16_t*)(ws + OFF_SH);

  hipLaunchKernelGGL(kprep_w, dim3((3*GG*192 + 255)/256), dim3(256), 0, stream,
                     wih0, whh0, wih1, whh1, wih2, whh2, wih16, whh16);

  for (int i = 0; i < NLAUNCH; ++i) {
    hipLaunchKernelGGL(kstep, dim3(96), dim3(256), 0, stream,
                       i, lengths, x, b0, b1, b2,
                       (const uint16_t*)wih16, (const uint16_t*)whh16,
                       gxw, hrw, scw, shw);
  }

  hipLaunchKernelGGL(kfc, dim3(64), dim3(64), 0, stream,
                     fcw, fcb, shw, (float*)d_out);
}